// Round 9
// baseline (456.698 us; speedup 1.0000x reference)
//
#include <hip/hip_runtime.h>
#include <hip/hip_cooperative_groups.h>

#define N_NODES 100000
#define N_EDGES 400000
#define D 128
#define BN_EPS 1e-5f
#define NTILES 6250   // N_NODES/16
#define COOP_GRID 512 // 2 blocks/CU x 256 CU — guaranteed co-resident at our reg/LDS tier

typedef short short8 __attribute__((ext_vector_type(8)));   // 8 bf16 as raw shorts (4 VGPRs)
typedef float f32x4 __attribute__((ext_vector_type(4)));

static __device__ __forceinline__ float bf2f(unsigned short u) {
    unsigned x = ((unsigned)u) << 16;
    return __builtin_bit_cast(float, x);
}
static __device__ __forceinline__ unsigned short f2bf(float f) {
    unsigned x = __builtin_bit_cast(unsigned, f);
    x += 0x7fffu + ((x >> 16) & 1u);   // round-to-nearest-even
    return (unsigned short)(x >> 16);
}
// split f32 into bf16 hi + bf16 lo (a ~= hi + lo, residual ~2^-17 rel)
static __device__ __forceinline__ void splitbf(float a, short& hi, short& lo) {
    unsigned short h = f2bf(a);
    float r = a - bf2f(h);
    hi = (short)h;
    lo = (short)f2bf(r);
}
static __device__ __forceinline__ void split2(float a, float b, unsigned& hiw, unsigned& low) {
    short ha, la, hb, lb;
    splitbf(a, ha, la);
    splitbf(b, hb, lb);
    hiw = (unsigned)(unsigned short)ha | ((unsigned)(unsigned short)hb << 16);
    low = (unsigned)(unsigned short)la | ((unsigned)(unsigned short)lb << 16);
}
// split 8 f32 (two f32x4) -> uint4 hi-plane + uint4 lo-plane (8 bf16 each)
static __device__ __forceinline__ void split8(f32x4 a, f32x4 b, uint4& hi, uint4& lo) {
    unsigned h0, h1, h2, h3, l0, l1, l2, l3;
    split2(a[0], a[1], h0, l0);
    split2(a[2], a[3], h1, l1);
    split2(b[0], b[1], h2, l2);
    split2(b[2], b[3], h3, l3);
    hi = uint4{h0, h1, h2, h3};
    lo = uint4{l0, l1, l2, l3};
}

// ---------------------------------------------------------------- fallback: clean zero-fill of d_out
__global__ void k_zero_out(float* __restrict__ y, int n4) {
    int t = blockIdx.x * blockDim.x + threadIdx.x;
    if (t < n4) ((float4*)y)[t] = float4{0.f, 0.f, 0.f, 0.f};
}

// ---------------------------------------------------------------- degree histograms
__global__ void k_count(const int* __restrict__ src, const int* __restrict__ dst,
                        int* __restrict__ cnt_src, int* __restrict__ cnt_dst) {
    int t = blockIdx.x * blockDim.x + threadIdx.x;
    if (t >= N_EDGES) return;
    atomicAdd(&cnt_src[src[t]], 1);
    atomicAdd(&cnt_dst[dst[t]], 1);
}

// ---------------------------------------------------------------- exclusive scan level 1 + coeffs (merged)
__global__ void k_scan1(const int* __restrict__ cnt, int* __restrict__ outp,
                        int* __restrict__ bsum,
                        const int* __restrict__ cnt_src,
                        float* __restrict__ c_src, float* __restrict__ c_dst,
                        int* __restrict__ fill) {
    __shared__ int s[256];
    int i = blockIdx.x * 256 + threadIdx.x;
    int v = (i < N_NODES) ? cnt[i] : 0;
    // merged k_coeffs: rsqrt coefficients + zero the fill cursors
    if (i < N_NODES) {
        c_src[i] = rsqrtf(fmaxf((float)cnt_src[i], 1.0f));
        c_dst[i] = rsqrtf(fmaxf((float)v, 1.0f));
        fill[i] = 0;
    }
    s[threadIdx.x] = v;
    __syncthreads();
    for (int d = 1; d < 256; d <<= 1) {
        int t = (threadIdx.x >= d) ? s[threadIdx.x - d] : 0;
        __syncthreads();
        s[threadIdx.x] += t;
        __syncthreads();
    }
    if (i < N_NODES) outp[i] = s[threadIdx.x] - v;   // exclusive
    if (threadIdx.x == 255) bsum[blockIdx.x] = s[255];
}

// ---------------------------------------------------------------- exclusive scan, level 2 (single block, nb<=512)
__global__ void k_scan2(int* __restrict__ bsum, int nb) {
    __shared__ int s[512];
    int v = (threadIdx.x < nb) ? bsum[threadIdx.x] : 0;
    s[threadIdx.x] = v;
    __syncthreads();
    for (int d = 1; d < 512; d <<= 1) {
        int t = (threadIdx.x >= d) ? s[threadIdx.x - d] : 0;
        __syncthreads();
        s[threadIdx.x] += t;
        __syncthreads();
    }
    if (threadIdx.x < nb) bsum[threadIdx.x] = s[threadIdx.x] - v;
}

// ---------------------------------------------------------------- scan fixup
__global__ void k_scan3(int* __restrict__ rowStart, const int* __restrict__ boff) {
    int i = blockIdx.x * 256 + threadIdx.x;
    if (i < N_NODES) rowStart[i] += boff[i >> 8];
    if (i == 0) rowStart[N_NODES] = N_EDGES;
}

// ---------------------------------------------------------------- bucket-fill: edge srcs sorted by dst
__global__ void k_fill(const int* __restrict__ src, const int* __restrict__ dst,
                       const int* __restrict__ rowStart, int* __restrict__ fill,
                       int* __restrict__ esorted) {
    int e = blockIdx.x * blockDim.x + threadIdx.x;
    if (e >= N_EDGES) return;
    int d = dst[e];
    int pos = rowStart[d] + atomicAdd(&fill[d], 1);
    esorted[pos] = src[e];
}

// ---------------------------------------------------------------- W(f32) -> MFMA B-fragment order, split hi/lo bf16
__global__ void k_make_frags(const float* __restrict__ W,
                             const float* __restrict__ Wr,
                             unsigned short* __restrict__ Whi, unsigned short* __restrict__ Wlo,
                             unsigned short* __restrict__ Wrhi, unsigned short* __restrict__ Wrlo) {
    int t = blockIdx.x * blockDim.x + threadIdx.x;   // 0..4095
    if (t >= 4096) return;
    int mat = t >> 11;
    int fragIdx = (t >> 6) & 31;
    int lane = t & 63;
    int nt = fragIdx >> 2, ks = fragIdx & 3;
    const float* Wsrc = mat ? Wr : W;
    unsigned short* dhi = mat ? Wrhi : Whi;
    unsigned short* dlo = mat ? Wrlo : Wlo;
    int n = nt * 16 + (lane & 15);
    int kbase = ks * 32 + (lane >> 4) * 8;
    short hi[8], lo[8];
#pragma unroll
    for (int j = 0; j < 8; j++) splitbf(Wsrc[(kbase + j) * D + n], hi[j], lo[j]);
    ((uint4*)dhi)[fragIdx * 64 + lane] = *(uint4*)hi;
    ((uint4*)dlo)[fragIdx * 64 + lane] = *(uint4*)lo;
}

// ---------------------------------------------------------------- FUSED gather + dual GEMM + (coop) BN
// PIPELINED: after the per-tile barrier, issue tile t+1's gather loads staged between
// tile t's MFMA clusters (idx loads -> accH MFMAs -> c loads -> accR MFMAs -> row loads
// -> epilogue -> accumulate/split/write). Each dependent-load latency hides under
// compute; gather duty-cycle (the 2.37/3.4 TB/s gap of r8) goes toward 1.
// coop=1 (hipLaunchCooperativeKernel, grid=COOP_GRID): BN stats+apply fused via grid
// sync; y is L3-hot. coop=0: plain launch, external bn kernels.
// DO NOT raise launch_bounds min-waves (r6: evicted weights). Occupancy is reg-tier
// capped at 2 blocks/CU; the pipeline compensates with per-wave overlap.
__global__ __launch_bounds__(256, 2) void k_fused(
    const float* __restrict__ x,
    const int* __restrict__ esorted, const int* __restrict__ rowStart,
    const float* __restrict__ c_src, const float* __restrict__ c_dst,
    const unsigned short* __restrict__ Whi, const unsigned short* __restrict__ Wlo,
    const unsigned short* __restrict__ Wrhi, const unsigned short* __restrict__ Wrlo,
    const float* __restrict__ bias_h, const float* __restrict__ bias_r,
    float* __restrict__ yout,
    float* __restrict__ gsum, float* __restrict__ gsq,
    const float* __restrict__ gamma, const float* __restrict__ beta,
    int coop) {
    __shared__ uint4 A[2][16][64];    // 32 KB double-buffered A-tile
    __shared__ float Y[4][16 * 36];   // 9.2 KB per-wave private staging
    __shared__ float sc[128], sh[128];

    const int wave = threadIdx.x >> 6;
    const int lane = threadIdx.x & 63;
    const int quad = lane >> 4;
    const int l16 = lane & 15;
    const int R = wave * 4 + quad;    // row within tile (this quad's node)
    const int li = l16;               // feature octet index
    float* __restrict__ ldsY = &Y[wave][0];
    const f32x4* __restrict__ xb = (const f32x4*)x;

    // ---- preload this wave's 32-col weight frags into VGPRs (128 VGPR)
    short8 wHf[8], wLf[8], rHf[8], rLf[8];
#pragma unroll
    for (int f = 0; f < 8; f++) {
        int nt = wave * 2 + (f >> 2), ks = f & 3;
        int gi = (nt * 4 + ks) * 64 + lane;
        wHf[f] = __builtin_bit_cast(short8, ((const uint4*)Whi)[gi]);
        wLf[f] = __builtin_bit_cast(short8, ((const uint4*)Wlo)[gi]);
        rHf[f] = __builtin_bit_cast(short8, ((const uint4*)Wrhi)[gi]);
        rLf[f] = __builtin_bit_cast(short8, ((const uint4*)Wrlo)[gi]);
    }
    float bh[2], brr[2];
#pragma unroll
    for (int ntl = 0; ntl < 2; ntl++) {
        int col = wave * 32 + ntl * 16 + l16;
        bh[ntl] = bias_h[col];
        brr[ntl] = bias_r[col];
    }

    float s_acc[2] = {0.f, 0.f}, q_acc[2] = {0.f, 0.f};
    const int rt0 = blockIdx.x;
    const int G = gridDim.x;

    // ---- prologue: full gather of tile rt0 into buf 0
    {
        const int n = rt0 * 16 + R;
        const int beg = rowStart[n], end = rowStart[n + 1];
        f32x4 X0 = xb[(size_t)n * 32 + li * 2], X1 = xb[(size_t)n * 32 + li * 2 + 1];
        f32x4 A0 = {0.f, 0.f, 0.f, 0.f}, A1 = {0.f, 0.f, 0.f, 0.f};
        for (int j = beg; j < end; j += 8) {
            int idx[8]; float c[8]; f32x4 pa[8], pb[8];
#pragma unroll
            for (int k = 0; k < 8; k++) {
                int jj = j + k;
                idx[k] = esorted[(jj < end) ? jj : j];
            }
#pragma unroll
            for (int k = 0; k < 8; k++) c[k] = (j + k < end) ? c_src[idx[k]] : 0.f;
#pragma unroll
            for (int k = 0; k < 8; k++) {
                pa[k] = xb[(size_t)idx[k] * 32 + li * 2];
                pb[k] = xb[(size_t)idx[k] * 32 + li * 2 + 1];
            }
#pragma unroll
            for (int k = 0; k < 8; k++) { A0 += pa[k] * c[k]; A1 += pb[k] * c[k]; }
        }
        float cd = c_dst[n];
        A0 *= cd; A1 *= cd;
        uint4 ahi, alo, xhi, xlo;
        split8(A0, A1, ahi, alo);
        split8(X0, X1, xhi, xlo);
        uint4* Arow = &A[0][R][0];
        const int sw = li ^ (R & 7);
        Arow[sw] = ahi; Arow[16 + sw] = alo; Arow[32 + sw] = xhi; Arow[48 + sw] = xlo;
    }
    // ---- prefetch next tile's row range
    int beg1 = 0, end1 = 0;
    if (rt0 + G < NTILES) {
        int n1 = (rt0 + G) * 16 + R;
        beg1 = rowStart[n1];
        end1 = rowStart[n1 + 1];
    }

    int buf = 0;
    for (int rt = rt0; rt < NTILES; rt += G, buf ^= 1) {
        const int rowbase = rt * 16;
        const int rtn = rt + G;
        const bool pf = rtn < NTILES;
        const int n1 = rtn * 16 + R;

        __syncthreads();   // buf[buf] ready (prologue or previous iteration's write)

        // ---- pipeline stage 1: next tile's edge indices (latency hides under MFMA)
        int idx[8];
        if (pf) {
#pragma unroll
            for (int k = 0; k < 8; k++) {
                int jj = beg1 + k;
                idx[k] = esorted[(jj < end1) ? jj : beg1];
            }
        }

        // ---- phase B: ds_read frags from buf
        const uint4* rowA = &A[buf][l16][0];
        const int r7 = l16 & 7;
        short8 aH[4], aL[4], xH[4], xL[4];
#pragma unroll
        for (int ks = 0; ks < 4; ks++) {
            const int sl = (ks * 4 + quad) ^ r7;
            aH[ks] = __builtin_bit_cast(short8, rowA[sl]);
            aL[ks] = __builtin_bit_cast(short8, rowA[16 + sl]);
            xH[ks] = __builtin_bit_cast(short8, rowA[32 + sl]);
            xL[ks] = __builtin_bit_cast(short8, rowA[48 + sl]);
        }

        // ---- MFMA cluster 1: GraphConv branch (aH/aL x wH/wL)
        f32x4 accH[2], accR[2];
#pragma unroll
        for (int ntl = 0; ntl < 2; ntl++) {
            accH[ntl] = f32x4{0.f, 0.f, 0.f, 0.f};
#pragma unroll
            for (int ks = 0; ks < 4; ks++) {
                const int f = ntl * 4 + ks;
                accH[ntl] = __builtin_amdgcn_mfma_f32_16x16x32_bf16(aH[ks], wHf[f], accH[ntl], 0, 0, 0);
                accH[ntl] = __builtin_amdgcn_mfma_f32_16x16x32_bf16(aH[ks], wLf[f], accH[ntl], 0, 0, 0);
                accH[ntl] = __builtin_amdgcn_mfma_f32_16x16x32_bf16(aL[ks], wHf[f], accH[ntl], 0, 0, 0);
            }
        }

        // ---- pipeline stage 2: coefficient loads (address-dep on idx, hidden by cluster 1)
        float c[8];
        if (pf) {
#pragma unroll
            for (int k = 0; k < 8; k++) c[k] = (beg1 + k < end1) ? c_src[idx[k]] : 0.f;
        }

        // ---- MFMA cluster 2: residual branch (xH/xL x rH/rL)
#pragma unroll
        for (int ntl = 0; ntl < 2; ntl++) {
            accR[ntl] = f32x4{0.f, 0.f, 0.f, 0.f};
#pragma unroll
            for (int ks = 0; ks < 4; ks++) {
                const int f = ntl * 4 + ks;
                accR[ntl] = __builtin_amdgcn_mfma_f32_16x16x32_bf16(xH[ks], rHf[f], accR[ntl], 0, 0, 0);
                accR[ntl] = __builtin_amdgcn_mfma_f32_16x16x32_bf16(xH[ks], rLf[f], accR[ntl], 0, 0, 0);
                accR[ntl] = __builtin_amdgcn_mfma_f32_16x16x32_bf16(xL[ks], rHf[f], accR[ntl], 0, 0, 0);
            }
        }

        // ---- pipeline stage 3: row loads (16 x 16B in flight across the epilogue)
        f32x4 pa[8], pb[8], X0n, X1n;
        if (pf) {
#pragma unroll
            for (int k = 0; k < 8; k++) {
                pa[k] = xb[(size_t)idx[k] * 32 + li * 2];
                pb[k] = xb[(size_t)idx[k] * 32 + li * 2 + 1];
            }
            X0n = xb[(size_t)n1 * 32 + li * 2];
            X1n = xb[(size_t)n1 * 32 + li * 2 + 1];
        }

        // ---- epilogue: per-wave LDS staging + BN partials (no cross-wave sync)
#pragma unroll
        for (int ntl = 0; ntl < 2; ntl++) {
            float s = 0.f, q = 0.f;
#pragma unroll
            for (int r = 0; r < 4; r++) {
                float y = fmaxf(accH[ntl][r] + bh[ntl], 0.f) + fmaxf(accR[ntl][r] + brr[ntl], 0.f);
                ldsY[(quad * 4 + r) * 36 + ntl * 16 + l16] = y;
                s += y;
                q += y * y;
            }
            s_acc[ntl] += s;
            q_acc[ntl] += q;
        }
        asm volatile("s_waitcnt lgkmcnt(0)");
#pragma unroll
        for (int j = 0; j < 2; j++) {
            int trow = j * 8 + (lane >> 3);
            int tc4 = lane & 7;
            float4 v = *(const float4*)&ldsY[trow * 36 + tc4 * 4];
            ((float4*)(yout + (size_t)(rowbase + trow) * D + wave * 32))[tc4] = v;
        }

        // ---- finish next tile's gather: accumulate, (rare) overflow rounds, split, write
        if (pf) {
            f32x4 A0 = {0.f, 0.f, 0.f, 0.f}, A1 = {0.f, 0.f, 0.f, 0.f};
#pragma unroll
            for (int k = 0; k < 8; k++) { A0 += pa[k] * c[k]; A1 += pb[k] * c[k]; }
            for (int j = beg1 + 8; j < end1; j += 8) {   // deg>8: ~2% of nodes
                int idx2[8]; float c2[8]; f32x4 qa[8], qb[8];
#pragma unroll
                for (int k = 0; k < 8; k++) {
                    int jj = j + k;
                    idx2[k] = esorted[(jj < end1) ? jj : j];
                }
#pragma unroll
                for (int k = 0; k < 8; k++) c2[k] = (j + k < end1) ? c_src[idx2[k]] : 0.f;
#pragma unroll
                for (int k = 0; k < 8; k++) {
                    qa[k] = xb[(size_t)idx2[k] * 32 + li * 2];
                    qb[k] = xb[(size_t)idx2[k] * 32 + li * 2 + 1];
                }
#pragma unroll
                for (int k = 0; k < 8; k++) { A0 += qa[k] * c2[k]; A1 += qb[k] * c2[k]; }
            }
            float cd = c_dst[n1];
            A0 *= cd; A1 *= cd;
            uint4 ahi, alo, xhi, xlo;
            split8(A0, A1, ahi, alo);
            split8(X0n, X1n, xhi, xlo);
            uint4* Arow = &A[buf ^ 1][R][0];
            const int sw = li ^ (R & 7);
            Arow[sw] = ahi; Arow[16 + sw] = alo; Arow[32 + sw] = xhi; Arow[48 + sw] = xlo;
            // prefetch row range for the tile after next
            int rt2 = rtn + G;
            if (rt2 < NTILES) {
                int n2 = rt2 * 16 + R;
                beg1 = rowStart[n2];
                end1 = rowStart[n2 + 1];
            }
        }
    }

    // ---- per-wave stats: quads hold same column set
#pragma unroll
    for (int ntl = 0; ntl < 2; ntl++) {
        float s = s_acc[ntl], q = q_acc[ntl];
        s += __shfl_xor(s, 16, 64);
        s += __shfl_xor(s, 32, 64);
        q += __shfl_xor(q, 16, 64);
        q += __shfl_xor(q, 32, 64);
        if (lane < 16) {
            unsafeAtomicAdd(&gsum[wave * 32 + ntl * 16 + lane], s);
            unsafeAtomicAdd(&gsq[wave * 32 + ntl * 16 + lane], q);
        }
    }

    // ---- cooperative BN tail (y is L3-hot; saves 2 launches + a cold 51 MB read)
    if (coop) {
        cooperative_groups::this_grid().sync();
        if (threadIdx.x < 128) {
            int f = threadIdx.x;
            float s = __hip_atomic_load(&gsum[f], __ATOMIC_RELAXED, __HIP_MEMORY_SCOPE_AGENT);
            float q = __hip_atomic_load(&gsq[f], __ATOMIC_RELAXED, __HIP_MEMORY_SCOPE_AGENT);
            const float invN = 1.0f / (float)N_NODES;
            float mean = s * invN;
            float var = fmaxf(q * invN - mean * mean, 0.f);
            float scl = gamma[f] * rsqrtf(var + BN_EPS);
            sc[f] = scl;
            sh[f] = beta[f] - mean * scl;
        }
        __syncthreads();
        const int total4 = N_NODES * D / 4;
        for (int i = blockIdx.x * blockDim.x + threadIdx.x; i < total4; i += gridDim.x * blockDim.x) {
            float4 v = ((float4*)yout)[i];
            int f = (i * 4) & (D - 1);
            v.x = v.x * sc[f] + sh[f];
            v.y = v.y * sc[f + 1] + sh[f + 1];
            v.z = v.z * sc[f + 2] + sh[f + 2];
            v.w = v.w * sc[f + 3] + sh[f + 3];
            ((float4*)yout)[i] = v;
        }
    }
}

// ---------------------------------------------------------------- BN stats -> scale/shift (fallback path)
__global__ void k_bn_stats(const float* __restrict__ gsum, const float* __restrict__ gsq,
                           const float* __restrict__ gamma, const float* __restrict__ beta,
                           float* __restrict__ scale, float* __restrict__ shift) {
    int f = threadIdx.x;   // 128 threads
    const float invN = 1.0f / (float)N_NODES;
    float mean = gsum[f] * invN;
    float var = fmaxf(gsq[f] * invN - mean * mean, 0.f);
    float sc = gamma[f] * rsqrtf(var + BN_EPS);
    scale[f] = sc;
    shift[f] = beta[f] - mean * sc;
}

// ---------------------------------------------------------------- apply BN in-place (fallback path)
__global__ void k_bn_apply(float* __restrict__ y,
                           const float* __restrict__ scale, const float* __restrict__ shift) {
    int t = blockIdx.x * blockDim.x + threadIdx.x;
    const int total4 = N_NODES * D / 4;
    if (t >= total4) return;
    float4 v = ((float4*)y)[t];
    int f = (t * 4) & (D - 1);
    v.x = v.x * scale[f] + shift[f];
    v.y = v.y * scale[f + 1] + shift[f + 1];
    v.z = v.z * scale[f + 2] + shift[f + 2];
    v.w = v.w * scale[f + 3] + shift[f + 3];
    ((float4*)y)[t] = v;
}

// ---------------------------------------------------------------- launch
extern "C" void kernel_launch(void* const* d_in, const int* in_sizes, int n_in,
                              void* d_out, int out_size, void* d_ws, size_t ws_size,
                              hipStream_t stream) {
    const float* x     = (const float*)d_in[0];   // node_feats f32 [N,128]
    const float* W     = (const float*)d_in[1];
    const float* b     = (const float*)d_in[2];
    const float* Wr    = (const float*)d_in[3];
    const float* br    = (const float*)d_in[4];
    const float* gamma = (const float*)d_in[5];
    const float* beta  = (const float*)d_in[6];
    const int* src = (const int*)d_in[7];
    const int* dst = (const int*)d_in[8];
    float* out = (float*)d_out;

    const int NB1 = (N_NODES + 255) / 256;   // 391 scan blocks

    char* ws = (char*)d_ws;
    size_t off = 0;
    // ---- zeroed prefix (one contiguous memset, ~0.8 MB) ----
    float* gsum    = (float*)(ws + off); off += 512;
    float* gsq     = (float*)(ws + off); off += 512;
    int* cnt_src   = (int*)(ws + off); off += 400128;   // N*4 padded to 256
    int* cnt_dst   = (int*)(ws + off); off += 400128;
    const size_t zero_bytes = off;
    // ---- non-zeroed scratch ----
    int* fill      = (int*)(ws + off); off += 400128;   // zeroed by k_scan1
    int* rowStart  = (int*)(ws + off); off += 400384;   // (N+1)*4 padded
    int* bsum      = (int*)(ws + off); off += 2048;     // NB1*4 padded
    int* esorted   = (int*)(ws + off); off += (size_t)N_EDGES * 4;   // 1.6 MB
    float* c_src   = (float*)(ws + off); off += 400128;
    float* c_dst   = (float*)(ws + off); off += 400128;
    unsigned short* WhiF  = (unsigned short*)(ws + off); off += 32768;
    unsigned short* WloF  = (unsigned short*)(ws + off); off += 32768;
    unsigned short* WrhiF = (unsigned short*)(ws + off); off += 32768;
    unsigned short* WrloF = (unsigned short*)(ws + off); off += 32768;
    float* scale = (float*)(ws + off); off += 512;
    float* shift = (float*)(ws + off); off += 512;
    const size_t needed = off;   // ~4.3 MB

    if (ws_size < needed) {
        k_zero_out<<<(N_NODES * D / 4 + 255) / 256, 256, 0, stream>>>(out, N_NODES * D / 4);
        return;
    }

    hipMemsetAsync(d_ws, 0, zero_bytes, stream);

    k_make_frags<<<16, 256, 0, stream>>>(W, Wr, WhiF, WloF, WrhiF, WrloF);
    // ---- counting sort of edges by dst ----
    k_count<<<(N_EDGES + 255) / 256, 256, 0, stream>>>(src, dst, cnt_src, cnt_dst);
    k_scan1<<<NB1, 256, 0, stream>>>(cnt_dst, rowStart, bsum, cnt_src, c_src, c_dst, fill);
    k_scan2<<<1, 512, 0, stream>>>(bsum, NB1);
    k_scan3<<<NB1, 256, 0, stream>>>(rowStart, bsum);
    k_fill<<<(N_EDGES + 255) / 256, 256, 0, stream>>>(src, dst, rowStart, fill, esorted);

    // ---- fused gather + dual GEMM + BN (cooperative; fallback to split path) ----
    int coopFlag = 1;
    void* kargs[] = {
        (void*)&x, (void*)&esorted, (void*)&rowStart, (void*)&c_src, (void*)&c_dst,
        (void*)&WhiF, (void*)&WloF, (void*)&WrhiF, (void*)&WrloF,
        (void*)&b, (void*)&br, (void*)&out, (void*)&gsum, (void*)&gsq,
        (void*)&gamma, (void*)&beta, (void*)&coopFlag
    };
    hipError_t ce = hipLaunchCooperativeKernel((const void*)k_fused, dim3(COOP_GRID), dim3(256),
                                               kargs, 0, stream);
    if (ce != hipSuccess) {
        (void)hipGetLastError();   // clear error state
        k_fused<<<1024, 256, 0, stream>>>(x, esorted, rowStart, c_src, c_dst,
                                          WhiF, WloF, WrhiF, WrloF, b, br, out,
                                          gsum, gsq, gamma, beta, 0);
        k_bn_stats<<<1, 128, 0, stream>>>(gsum, gsq, gamma, beta, scale, shift);
        k_bn_apply<<<(N_NODES * D / 4 + 255) / 256, 256, 0, stream>>>(out, scale, shift);
    }
}

// Round 10
// 354.490 us; speedup vs baseline: 1.2883x; 1.2883x over previous
//
#include <hip/hip_runtime.h>
#include <hip/hip_cooperative_groups.h>

#define N_NODES 100000
#define N_EDGES 400000
#define D 128
#define BN_EPS 1e-5f
#define NTILES 6250   // N_NODES/16
#define COOP_GRID 512 // 2 blocks/CU x 256 CU — co-resident at our reg/LDS tier

typedef short short8 __attribute__((ext_vector_type(8)));   // 8 bf16 as raw shorts (4 VGPRs)
typedef float f32x4 __attribute__((ext_vector_type(4)));

static __device__ __forceinline__ float bf2f(unsigned short u) {
    unsigned x = ((unsigned)u) << 16;
    return __builtin_bit_cast(float, x);
}
static __device__ __forceinline__ unsigned short f2bf(float f) {
    unsigned x = __builtin_bit_cast(unsigned, f);
    x += 0x7fffu + ((x >> 16) & 1u);   // round-to-nearest-even
    return (unsigned short)(x >> 16);
}
// split f32 into bf16 hi + bf16 lo (a ~= hi + lo, residual ~2^-17 rel)
static __device__ __forceinline__ void splitbf(float a, short& hi, short& lo) {
    unsigned short h = f2bf(a);
    float r = a - bf2f(h);
    hi = (short)h;
    lo = (short)f2bf(r);
}
static __device__ __forceinline__ void split2(float a, float b, unsigned& hiw, unsigned& low) {
    short ha, la, hb, lb;
    splitbf(a, ha, la);
    splitbf(b, hb, lb);
    hiw = (unsigned)(unsigned short)ha | ((unsigned)(unsigned short)hb << 16);
    low = (unsigned)(unsigned short)la | ((unsigned)(unsigned short)lb << 16);
}
// split 8 f32 (two f32x4) -> uint4 hi-plane + uint4 lo-plane (8 bf16 each)
static __device__ __forceinline__ void split8(f32x4 a, f32x4 b, uint4& hi, uint4& lo) {
    unsigned h0, h1, h2, h3, l0, l1, l2, l3;
    split2(a[0], a[1], h0, l0);
    split2(a[2], a[3], h1, l1);
    split2(b[0], b[1], h2, l2);
    split2(b[2], b[3], h3, l3);
    hi = uint4{h0, h1, h2, h3};
    lo = uint4{l0, l1, l2, l3};
}

// ---------------------------------------------------------------- fallback: clean zero-fill of d_out
__global__ void k_zero_out(float* __restrict__ y, int n4) {
    int t = blockIdx.x * blockDim.x + threadIdx.x;
    if (t < n4) ((float4*)y)[t] = float4{0.f, 0.f, 0.f, 0.f};
}

// ---------------------------------------------------------------- degree histograms
__global__ void k_count(const int* __restrict__ src, const int* __restrict__ dst,
                        int* __restrict__ cnt_src, int* __restrict__ cnt_dst) {
    int t = blockIdx.x * blockDim.x + threadIdx.x;
    if (t >= N_EDGES) return;
    atomicAdd(&cnt_src[src[t]], 1);
    atomicAdd(&cnt_dst[dst[t]], 1);
}

// ---------------------------------------------------------------- exclusive scan level 1 + coeffs (merged)
__global__ void k_scan1(const int* __restrict__ cnt, int* __restrict__ outp,
                        int* __restrict__ bsum,
                        const int* __restrict__ cnt_src,
                        float* __restrict__ c_src, float* __restrict__ c_dst,
                        int* __restrict__ fill) {
    __shared__ int s[256];
    int i = blockIdx.x * 256 + threadIdx.x;
    int v = (i < N_NODES) ? cnt[i] : 0;
    if (i < N_NODES) {
        c_src[i] = rsqrtf(fmaxf((float)cnt_src[i], 1.0f));
        c_dst[i] = rsqrtf(fmaxf((float)v, 1.0f));
        fill[i] = 0;
    }
    s[threadIdx.x] = v;
    __syncthreads();
    for (int d = 1; d < 256; d <<= 1) {
        int t = (threadIdx.x >= d) ? s[threadIdx.x - d] : 0;
        __syncthreads();
        s[threadIdx.x] += t;
        __syncthreads();
    }
    if (i < N_NODES) outp[i] = s[threadIdx.x] - v;   // exclusive
    if (threadIdx.x == 255) bsum[blockIdx.x] = s[255];
}

// ---------------------------------------------------------------- exclusive scan, level 2 (single block, nb<=512)
__global__ void k_scan2(int* __restrict__ bsum, int nb) {
    __shared__ int s[512];
    int v = (threadIdx.x < nb) ? bsum[threadIdx.x] : 0;
    s[threadIdx.x] = v;
    __syncthreads();
    for (int d = 1; d < 512; d <<= 1) {
        int t = (threadIdx.x >= d) ? s[threadIdx.x - d] : 0;
        __syncthreads();
        s[threadIdx.x] += t;
        __syncthreads();
    }
    if (threadIdx.x < nb) bsum[threadIdx.x] = s[threadIdx.x] - v;
}

// ---------------------------------------------------------------- scan fixup
__global__ void k_scan3(int* __restrict__ rowStart, const int* __restrict__ boff) {
    int i = blockIdx.x * 256 + threadIdx.x;
    if (i < N_NODES) rowStart[i] += boff[i >> 8];
    if (i == 0) rowStart[N_NODES] = N_EDGES;
}

// ---------------------------------------------------------------- bucket-fill: edge srcs sorted by dst
__global__ void k_fill(const int* __restrict__ src, const int* __restrict__ dst,
                       const int* __restrict__ rowStart, int* __restrict__ fill,
                       int* __restrict__ esorted) {
    int e = blockIdx.x * blockDim.x + threadIdx.x;
    if (e >= N_EDGES) return;
    int d = dst[e];
    int pos = rowStart[d] + atomicAdd(&fill[d], 1);
    esorted[pos] = src[e];
}

// ---------------------------------------------------------------- W(f32) -> MFMA B-fragment order, split hi/lo bf16
__global__ void k_make_frags(const float* __restrict__ W,
                             const float* __restrict__ Wr,
                             unsigned short* __restrict__ Whi, unsigned short* __restrict__ Wlo,
                             unsigned short* __restrict__ Wrhi, unsigned short* __restrict__ Wrlo) {
    int t = blockIdx.x * blockDim.x + threadIdx.x;   // 0..4095
    if (t >= 4096) return;
    int mat = t >> 11;
    int fragIdx = (t >> 6) & 31;
    int lane = t & 63;
    int nt = fragIdx >> 2, ks = fragIdx & 3;
    const float* Wsrc = mat ? Wr : W;
    unsigned short* dhi = mat ? Wrhi : Whi;
    unsigned short* dlo = mat ? Wrlo : Wlo;
    int n = nt * 16 + (lane & 15);
    int kbase = ks * 32 + (lane >> 4) * 8;
    short hi[8], lo[8];
#pragma unroll
    for (int j = 0; j < 8; j++) splitbf(Wsrc[(kbase + j) * D + n], hi[j], lo[j]);
    ((uint4*)dhi)[fragIdx * 64 + lane] = *(uint4*)hi;
    ((uint4*)dlo)[fragIdx * 64 + lane] = *(uint4*)lo;
}

// ---------------------------------------------------------------- FUSED gather + dual GEMM + (coop) BN
// r8 structure (chunk-8 gather with SHORT-LIVED row registers) + LIGHT cross-phase
// prefetch: only idx[8]+c[8] (16 VGPRs) cross the MFMA clusters — r9's row-data
// prefetch (72 VGPRs live across epilogue) spilled to scratch (FETCH 452 MB). Row
// loads stay inside the gather section. Coop path fuses BN stats+apply via grid sync.
// DO NOT raise launch_bounds min-waves (r6: weight eviction).
__global__ __launch_bounds__(256, 2) void k_fused(
    const float* __restrict__ x,
    const int* __restrict__ esorted, const int* __restrict__ rowStart,
    const float* __restrict__ c_src, const float* __restrict__ c_dst,
    const unsigned short* __restrict__ Whi, const unsigned short* __restrict__ Wlo,
    const unsigned short* __restrict__ Wrhi, const unsigned short* __restrict__ Wrlo,
    const float* __restrict__ bias_h, const float* __restrict__ bias_r,
    float* __restrict__ yout,
    float* __restrict__ gsum, float* __restrict__ gsq,
    const float* __restrict__ gamma, const float* __restrict__ beta,
    int coop) {
    __shared__ uint4 A[2][16][64];    // 32 KB double-buffered A-tile
    __shared__ float Y[4][16 * 36];   // 9.2 KB per-wave private staging
    __shared__ float sc[128], sh[128];

    const int wave = threadIdx.x >> 6;
    const int lane = threadIdx.x & 63;
    const int quad = lane >> 4;
    const int l16 = lane & 15;
    const int R = wave * 4 + quad;    // row within tile (this quad's node)
    const int li = l16;               // feature octet index
    float* __restrict__ ldsY = &Y[wave][0];
    const f32x4* __restrict__ xb = (const f32x4*)x;

    // ---- preload this wave's 32-col weight frags into VGPRs (128 VGPR)
    short8 wHf[8], wLf[8], rHf[8], rLf[8];
#pragma unroll
    for (int f = 0; f < 8; f++) {
        int nt = wave * 2 + (f >> 2), ks = f & 3;
        int gi = (nt * 4 + ks) * 64 + lane;
        wHf[f] = __builtin_bit_cast(short8, ((const uint4*)Whi)[gi]);
        wLf[f] = __builtin_bit_cast(short8, ((const uint4*)Wlo)[gi]);
        rHf[f] = __builtin_bit_cast(short8, ((const uint4*)Wrhi)[gi]);
        rLf[f] = __builtin_bit_cast(short8, ((const uint4*)Wrlo)[gi]);
    }
    float bh[2], brr[2];
#pragma unroll
    for (int ntl = 0; ntl < 2; ntl++) {
        int col = wave * 32 + ntl * 16 + l16;
        bh[ntl] = bias_h[col];
        brr[ntl] = bias_r[col];
    }

    float s_acc[2] = {0.f, 0.f}, q_acc[2] = {0.f, 0.f};
    const int rt0 = blockIdx.x;
    const int G = gridDim.x;

    // ---- prologue: full gather of tile rt0 into buf 0 (chunk-8, rows short-lived)
    {
        const int n = rt0 * 16 + R;
        const int beg = rowStart[n], end = rowStart[n + 1];
        f32x4 X0 = xb[(size_t)n * 32 + li * 2], X1 = xb[(size_t)n * 32 + li * 2 + 1];
        f32x4 A0 = {0.f, 0.f, 0.f, 0.f}, A1 = {0.f, 0.f, 0.f, 0.f};
        for (int j = beg; j < end; j += 8) {
            int idx[8]; float c[8]; f32x4 pa[8], pb[8];
#pragma unroll
            for (int k = 0; k < 8; k++) {
                int jj = j + k;
                idx[k] = esorted[(jj < end) ? jj : j];
            }
#pragma unroll
            for (int k = 0; k < 8; k++) c[k] = (j + k < end) ? c_src[idx[k]] : 0.f;
#pragma unroll
            for (int k = 0; k < 8; k++) {
                pa[k] = xb[(size_t)idx[k] * 32 + li * 2];
                pb[k] = xb[(size_t)idx[k] * 32 + li * 2 + 1];
            }
#pragma unroll
            for (int k = 0; k < 8; k++) { A0 += pa[k] * c[k]; A1 += pb[k] * c[k]; }
        }
        float cd = c_dst[n];
        A0 *= cd; A1 *= cd;
        uint4 ahi, alo, xhi, xlo;
        split8(A0, A1, ahi, alo);
        split8(X0, X1, xhi, xlo);
        uint4* Arow = &A[0][R][0];
        const int sw = li ^ (R & 7);
        Arow[sw] = ahi; Arow[16 + sw] = alo; Arow[32 + sw] = xhi; Arow[48 + sw] = xlo;
    }
    // ---- prefetch next tile's row range
    int beg1 = 0, end1 = 0;
    if (rt0 + G < NTILES) {
        int n1 = (rt0 + G) * 16 + R;
        beg1 = rowStart[n1];
        end1 = rowStart[n1 + 1];
    }

    int buf = 0;
    for (int rt = rt0; rt < NTILES; rt += G, buf ^= 1) {
        const int rowbase = rt * 16;
        const int rtn = rt + G;
        const bool pf = rtn < NTILES;
        const int n1 = rtn * 16 + R;

        __syncthreads();   // A[buf] ready

        // ---- light prefetch stage 1: next tile's first-chunk edge indices (8 VGPRs)
        int idx[8];
        if (pf) {
#pragma unroll
            for (int k = 0; k < 8; k++) {
                int jj = beg1 + k;
                idx[k] = esorted[(jj < end1) ? jj : beg1];
            }
        }

        // ---- phase B: ds_read frags from buf
        const uint4* rowA = &A[buf][l16][0];
        const int r7 = l16 & 7;
        short8 aH[4], aL[4], xH[4], xL[4];
#pragma unroll
        for (int ks = 0; ks < 4; ks++) {
            const int sl = (ks * 4 + quad) ^ r7;
            aH[ks] = __builtin_bit_cast(short8, rowA[sl]);
            aL[ks] = __builtin_bit_cast(short8, rowA[16 + sl]);
            xH[ks] = __builtin_bit_cast(short8, rowA[32 + sl]);
            xL[ks] = __builtin_bit_cast(short8, rowA[48 + sl]);
        }

        // ---- MFMA cluster 1: GraphConv branch
        f32x4 accH[2], accR[2];
#pragma unroll
        for (int ntl = 0; ntl < 2; ntl++) {
            accH[ntl] = f32x4{0.f, 0.f, 0.f, 0.f};
#pragma unroll
            for (int ks = 0; ks < 4; ks++) {
                const int f = ntl * 4 + ks;
                accH[ntl] = __builtin_amdgcn_mfma_f32_16x16x32_bf16(aH[ks], wHf[f], accH[ntl], 0, 0, 0);
                accH[ntl] = __builtin_amdgcn_mfma_f32_16x16x32_bf16(aH[ks], wLf[f], accH[ntl], 0, 0, 0);
                accH[ntl] = __builtin_amdgcn_mfma_f32_16x16x32_bf16(aL[ks], wHf[f], accH[ntl], 0, 0, 0);
            }
        }

        // ---- light prefetch stage 2: coefficients (8 VGPRs; addr-dep hidden by cluster 1)
        float c[8];
        if (pf) {
#pragma unroll
            for (int k = 0; k < 8; k++) c[k] = (beg1 + k < end1) ? c_src[idx[k]] : 0.f;
        }

        // ---- MFMA cluster 2: residual branch
#pragma unroll
        for (int ntl = 0; ntl < 2; ntl++) {
            accR[ntl] = f32x4{0.f, 0.f, 0.f, 0.f};
#pragma unroll
            for (int ks = 0; ks < 4; ks++) {
                const int f = ntl * 4 + ks;
                accR[ntl] = __builtin_amdgcn_mfma_f32_16x16x32_bf16(xH[ks], rHf[f], accR[ntl], 0, 0, 0);
                accR[ntl] = __builtin_amdgcn_mfma_f32_16x16x32_bf16(xH[ks], rLf[f], accR[ntl], 0, 0, 0);
                accR[ntl] = __builtin_amdgcn_mfma_f32_16x16x32_bf16(xL[ks], rHf[f], accR[ntl], 0, 0, 0);
            }
        }

        // ---- epilogue: per-wave LDS staging + BN partials (no cross-wave sync)
#pragma unroll
        for (int ntl = 0; ntl < 2; ntl++) {
            float s = 0.f, q = 0.f;
#pragma unroll
            for (int r = 0; r < 4; r++) {
                float y = fmaxf(accH[ntl][r] + bh[ntl], 0.f) + fmaxf(accR[ntl][r] + brr[ntl], 0.f);
                ldsY[(quad * 4 + r) * 36 + ntl * 16 + l16] = y;
                s += y;
                q += y * y;
            }
            s_acc[ntl] += s;
            q_acc[ntl] += q;
        }
        asm volatile("s_waitcnt lgkmcnt(0)");
#pragma unroll
        for (int j = 0; j < 2; j++) {
            int trow = j * 8 + (lane >> 3);
            int tc4 = lane & 7;
            float4 v = *(const float4*)&ldsY[trow * 36 + tc4 * 4];
            ((float4*)(yout + (size_t)(rowbase + trow) * D + wave * 32))[tc4] = v;
        }

        // ---- gather next tile (rows SHORT-LIVED here — no spill), write to A[buf^1]
        if (pf) {
            f32x4 A0 = {0.f, 0.f, 0.f, 0.f}, A1 = {0.f, 0.f, 0.f, 0.f};
            {
                f32x4 pa[8], pb[8];
#pragma unroll
                for (int k = 0; k < 8; k++) {
                    pa[k] = xb[(size_t)idx[k] * 32 + li * 2];
                    pb[k] = xb[(size_t)idx[k] * 32 + li * 2 + 1];
                }
#pragma unroll
                for (int k = 0; k < 8; k++) { A0 += pa[k] * c[k]; A1 += pb[k] * c[k]; }
            }
            for (int j = beg1 + 8; j < end1; j += 8) {   // deg>8: ~2% of nodes
                int idx2[8]; float c2[8]; f32x4 qa[8], qb[8];
#pragma unroll
                for (int k = 0; k < 8; k++) {
                    int jj = j + k;
                    idx2[k] = esorted[(jj < end1) ? jj : j];
                }
#pragma unroll
                for (int k = 0; k < 8; k++) c2[k] = (j + k < end1) ? c_src[idx2[k]] : 0.f;
#pragma unroll
                for (int k = 0; k < 8; k++) {
                    qa[k] = xb[(size_t)idx2[k] * 32 + li * 2];
                    qb[k] = xb[(size_t)idx2[k] * 32 + li * 2 + 1];
                }
#pragma unroll
                for (int k = 0; k < 8; k++) { A0 += qa[k] * c2[k]; A1 += qb[k] * c2[k]; }
            }
            float cd = c_dst[n1];
            A0 *= cd; A1 *= cd;
            f32x4 X0 = xb[(size_t)n1 * 32 + li * 2], X1 = xb[(size_t)n1 * 32 + li * 2 + 1];
            uint4 ahi, alo, xhi, xlo;
            split8(A0, A1, ahi, alo);
            split8(X0, X1, xhi, xlo);
            uint4* Arow = &A[buf ^ 1][R][0];
            const int sw = li ^ (R & 7);
            Arow[sw] = ahi; Arow[16 + sw] = alo; Arow[32 + sw] = xhi; Arow[48 + sw] = xlo;
            // prefetch row range for the tile after next
            int rt2 = rtn + G;
            if (rt2 < NTILES) {
                int n2 = rt2 * 16 + R;
                beg1 = rowStart[n2];
                end1 = rowStart[n2 + 1];
            }
        }
    }

    // ---- per-wave stats: quads hold same column set
#pragma unroll
    for (int ntl = 0; ntl < 2; ntl++) {
        float s = s_acc[ntl], q = q_acc[ntl];
        s += __shfl_xor(s, 16, 64);
        s += __shfl_xor(s, 32, 64);
        q += __shfl_xor(q, 16, 64);
        q += __shfl_xor(q, 32, 64);
        if (lane < 16) {
            unsafeAtomicAdd(&gsum[wave * 32 + ntl * 16 + lane], s);
            unsafeAtomicAdd(&gsq[wave * 32 + ntl * 16 + lane], q);
        }
    }

    // ---- cooperative BN tail (y is L3-hot; saves 2 launches + a cold 51 MB read)
    if (coop) {
        cooperative_groups::this_grid().sync();
        if (threadIdx.x < 128) {
            int f = threadIdx.x;
            float s = __hip_atomic_load(&gsum[f], __ATOMIC_RELAXED, __HIP_MEMORY_SCOPE_AGENT);
            float q = __hip_atomic_load(&gsq[f], __ATOMIC_RELAXED, __HIP_MEMORY_SCOPE_AGENT);
            const float invN = 1.0f / (float)N_NODES;
            float mean = s * invN;
            float var = fmaxf(q * invN - mean * mean, 0.f);
            float scl = gamma[f] * rsqrtf(var + BN_EPS);
            sc[f] = scl;
            sh[f] = beta[f] - mean * scl;
        }
        __syncthreads();
        const int total4 = N_NODES * D / 4;
        for (int i = blockIdx.x * blockDim.x + threadIdx.x; i < total4; i += gridDim.x * blockDim.x) {
            float4 v = ((float4*)yout)[i];
            int f = (i * 4) & (D - 1);
            v.x = v.x * sc[f] + sh[f];
            v.y = v.y * sc[f + 1] + sh[f + 1];
            v.z = v.z * sc[f + 2] + sh[f + 2];
            v.w = v.w * sc[f + 3] + sh[f + 3];
            ((float4*)yout)[i] = v;
        }
    }
}

// ---------------------------------------------------------------- BN stats -> scale/shift (fallback path)
__global__ void k_bn_stats(const float* __restrict__ gsum, const float* __restrict__ gsq,
                           const float* __restrict__ gamma, const float* __restrict__ beta,
                           float* __restrict__ scale, float* __restrict__ shift) {
    int f = threadIdx.x;   // 128 threads
    const float invN = 1.0f / (float)N_NODES;
    float mean = gsum[f] * invN;
    float var = fmaxf(gsq[f] * invN - mean * mean, 0.f);
    float sc = gamma[f] * rsqrtf(var + BN_EPS);
    scale[f] = sc;
    shift[f] = beta[f] - mean * sc;
}

// ---------------------------------------------------------------- apply BN in-place (fallback path)
__global__ void k_bn_apply(float* __restrict__ y,
                           const float* __restrict__ scale, const float* __restrict__ shift) {
    int t = blockIdx.x * blockDim.x + threadIdx.x;
    const int total4 = N_NODES * D / 4;
    if (t >= total4) return;
    float4 v = ((float4*)y)[t];
    int f = (t * 4) & (D - 1);
    v.x = v.x * scale[f] + shift[f];
    v.y = v.y * scale[f + 1] + shift[f + 1];
    v.z = v.z * scale[f + 2] + shift[f + 2];
    v.w = v.w * scale[f + 3] + shift[f + 3];
    ((float4*)y)[t] = v;
}

// ---------------------------------------------------------------- launch
extern "C" void kernel_launch(void* const* d_in, const int* in_sizes, int n_in,
                              void* d_out, int out_size, void* d_ws, size_t ws_size,
                              hipStream_t stream) {
    const float* x     = (const float*)d_in[0];   // node_feats f32 [N,128]
    const float* W     = (const float*)d_in[1];
    const float* b     = (const float*)d_in[2];
    const float* Wr    = (const float*)d_in[3];
    const float* br    = (const float*)d_in[4];
    const float* gamma = (const float*)d_in[5];
    const float* beta  = (const float*)d_in[6];
    const int* src = (const int*)d_in[7];
    const int* dst = (const int*)d_in[8];
    float* out = (float*)d_out;

    const int NB1 = (N_NODES + 255) / 256;   // 391 scan blocks

    char* ws = (char*)d_ws;
    size_t off = 0;
    // ---- zeroed prefix (one contiguous memset, ~0.8 MB) ----
    float* gsum    = (float*)(ws + off); off += 512;
    float* gsq     = (float*)(ws + off); off += 512;
    int* cnt_src   = (int*)(ws + off); off += 400128;   // N*4 padded to 256
    int* cnt_dst   = (int*)(ws + off); off += 400128;
    const size_t zero_bytes = off;
    // ---- non-zeroed scratch ----
    int* fill      = (int*)(ws + off); off += 400128;   // zeroed by k_scan1
    int* rowStart  = (int*)(ws + off); off += 400384;   // (N+1)*4 padded
    int* bsum      = (int*)(ws + off); off += 2048;     // NB1*4 padded
    int* esorted   = (int*)(ws + off); off += (size_t)N_EDGES * 4;   // 1.6 MB
    float* c_src   = (float*)(ws + off); off += 400128;
    float* c_dst   = (float*)(ws + off); off += 400128;
    unsigned short* WhiF  = (unsigned short*)(ws + off); off += 32768;
    unsigned short* WloF  = (unsigned short*)(ws + off); off += 32768;
    unsigned short* WrhiF = (unsigned short*)(ws + off); off += 32768;
    unsigned short* WrloF = (unsigned short*)(ws + off); off += 32768;
    float* scale = (float*)(ws + off); off += 512;
    float* shift = (float*)(ws + off); off += 512;
    const size_t needed = off;   // ~4.3 MB

    if (ws_size < needed) {
        k_zero_out<<<(N_NODES * D / 4 + 255) / 256, 256, 0, stream>>>(out, N_NODES * D / 4);
        return;
    }

    hipMemsetAsync(d_ws, 0, zero_bytes, stream);

    k_make_frags<<<16, 256, 0, stream>>>(W, Wr, WhiF, WloF, WrhiF, WrloF);
    // ---- counting sort of edges by dst ----
    k_count<<<(N_EDGES + 255) / 256, 256, 0, stream>>>(src, dst, cnt_src, cnt_dst);
    k_scan1<<<NB1, 256, 0, stream>>>(cnt_dst, rowStart, bsum, cnt_src, c_src, c_dst, fill);
    k_scan2<<<1, 512, 0, stream>>>(bsum, NB1);
    k_scan3<<<NB1, 256, 0, stream>>>(rowStart, bsum);
    k_fill<<<(N_EDGES + 255) / 256, 256, 0, stream>>>(src, dst, rowStart, fill, esorted);

    // ---- fused gather + dual GEMM + BN (cooperative; fallback to split path) ----
    int coopFlag = 1;
    void* kargs[] = {
        (void*)&x, (void*)&esorted, (void*)&rowStart, (void*)&c_src, (void*)&c_dst,
        (void*)&WhiF, (void*)&WloF, (void*)&WrhiF, (void*)&WrloF,
        (void*)&b, (void*)&br, (void*)&out, (void*)&gsum, (void*)&gsq,
        (void*)&gamma, (void*)&beta, (void*)&coopFlag
    };
    hipError_t ce = hipLaunchCooperativeKernel((const void*)k_fused, dim3(COOP_GRID), dim3(256),
                                               kargs, 0, stream);
    if (ce != hipSuccess) {
        (void)hipGetLastError();   // clear error state
        k_fused<<<1024, 256, 0, stream>>>(x, esorted, rowStart, c_src, c_dst,
                                          WhiF, WloF, WrhiF, WrloF, b, br, out,
                                          gsum, gsq, gamma, beta, 0);
        k_bn_stats<<<1, 128, 0, stream>>>(gsum, gsq, gamma, beta, scale, shift);
        k_bn_apply<<<(N_NODES * D / 4 + 255) / 256, 256, 0, stream>>>(out, scale, shift);
    }
}

// Round 11
// 247.417 us; speedup vs baseline: 1.8459x; 1.4328x over previous
//
#include <hip/hip_runtime.h>

#define N_NODES 100000
#define N_EDGES 400000
#define D 128
#define BN_EPS 1e-5f
#define NTILES 6250   // N_NODES/16

typedef short short8 __attribute__((ext_vector_type(8)));   // 8 bf16 as raw shorts (4 VGPRs)
typedef float f32x4 __attribute__((ext_vector_type(4)));

static __device__ __forceinline__ float bf2f(unsigned short u) {
    unsigned x = ((unsigned)u) << 16;
    return __builtin_bit_cast(float, x);
}
static __device__ __forceinline__ unsigned short f2bf(float f) {
    unsigned x = __builtin_bit_cast(unsigned, f);
    x += 0x7fffu + ((x >> 16) & 1u);   // round-to-nearest-even
    return (unsigned short)(x >> 16);
}
// split f32 into bf16 hi + bf16 lo (a ~= hi + lo, residual ~2^-17 rel)
static __device__ __forceinline__ void splitbf(float a, short& hi, short& lo) {
    unsigned short h = f2bf(a);
    float r = a - bf2f(h);
    hi = (short)h;
    lo = (short)f2bf(r);
}
static __device__ __forceinline__ void split2(float a, float b, unsigned& hiw, unsigned& low) {
    short ha, la, hb, lb;
    splitbf(a, ha, la);
    splitbf(b, hb, lb);
    hiw = (unsigned)(unsigned short)ha | ((unsigned)(unsigned short)hb << 16);
    low = (unsigned)(unsigned short)la | ((unsigned)(unsigned short)lb << 16);
}
// split 8 f32 (two f32x4) -> uint4 hi-plane + uint4 lo-plane (8 bf16 each)
static __device__ __forceinline__ void split8(f32x4 a, f32x4 b, uint4& hi, uint4& lo) {
    unsigned h0, h1, h2, h3, l0, l1, l2, l3;
    split2(a[0], a[1], h0, l0);
    split2(a[2], a[3], h1, l1);
    split2(b[0], b[1], h2, l2);
    split2(b[2], b[3], h3, l3);
    hi = uint4{h0, h1, h2, h3};
    lo = uint4{l0, l1, l2, l3};
}

// ---------------------------------------------------------------- fallback: clean zero-fill of d_out
__global__ void k_zero_out(float* __restrict__ y, int n4) {
    int t = blockIdx.x * blockDim.x + threadIdx.x;
    if (t < n4) ((float4*)y)[t] = float4{0.f, 0.f, 0.f, 0.f};
}

// ---------------------------------------------------------------- degree histograms
__global__ void k_count(const int* __restrict__ src, const int* __restrict__ dst,
                        int* __restrict__ cnt_src, int* __restrict__ cnt_dst) {
    int t = blockIdx.x * blockDim.x + threadIdx.x;
    if (t >= N_EDGES) return;
    atomicAdd(&cnt_src[src[t]], 1);
    atomicAdd(&cnt_dst[dst[t]], 1);
}

// ---------------------------------------------------------------- exclusive scan level 1 + coeffs (merged)
__global__ void k_scan1(const int* __restrict__ cnt, int* __restrict__ outp,
                        int* __restrict__ bsum,
                        const int* __restrict__ cnt_src,
                        float* __restrict__ c_src, float* __restrict__ c_dst,
                        int* __restrict__ fill) {
    __shared__ int s[256];
    int i = blockIdx.x * 256 + threadIdx.x;
    int v = (i < N_NODES) ? cnt[i] : 0;
    // merged coeffs: rsqrt coefficients + zero the fill cursors
    if (i < N_NODES) {
        c_src[i] = rsqrtf(fmaxf((float)cnt_src[i], 1.0f));
        c_dst[i] = rsqrtf(fmaxf((float)v, 1.0f));
        fill[i] = 0;
    }
    s[threadIdx.x] = v;
    __syncthreads();
    for (int d = 1; d < 256; d <<= 1) {
        int t = (threadIdx.x >= d) ? s[threadIdx.x - d] : 0;
        __syncthreads();
        s[threadIdx.x] += t;
        __syncthreads();
    }
    if (i < N_NODES) outp[i] = s[threadIdx.x] - v;   // exclusive
    if (threadIdx.x == 255) bsum[blockIdx.x] = s[255];
}

// ---------------------------------------------------------------- exclusive scan, level 2 (single block, nb<=512)
__global__ void k_scan2(int* __restrict__ bsum, int nb) {
    __shared__ int s[512];
    int v = (threadIdx.x < nb) ? bsum[threadIdx.x] : 0;
    s[threadIdx.x] = v;
    __syncthreads();
    for (int d = 1; d < 512; d <<= 1) {
        int t = (threadIdx.x >= d) ? s[threadIdx.x - d] : 0;
        __syncthreads();
        s[threadIdx.x] += t;
        __syncthreads();
    }
    if (threadIdx.x < nb) bsum[threadIdx.x] = s[threadIdx.x] - v;
}

// ---------------------------------------------------------------- scan fixup
__global__ void k_scan3(int* __restrict__ rowStart, const int* __restrict__ boff) {
    int i = blockIdx.x * 256 + threadIdx.x;
    if (i < N_NODES) rowStart[i] += boff[i >> 8];
    if (i == 0) rowStart[N_NODES] = N_EDGES;
}

// ---------------------------------------------------------------- bucket-fill: edge srcs sorted by dst
__global__ void k_fill(const int* __restrict__ src, const int* __restrict__ dst,
                       const int* __restrict__ rowStart, int* __restrict__ fill,
                       int* __restrict__ esorted) {
    int e = blockIdx.x * blockDim.x + threadIdx.x;
    if (e >= N_EDGES) return;
    int d = dst[e];
    int pos = rowStart[d] + atomicAdd(&fill[d], 1);
    esorted[pos] = src[e];
}

// ---------------------------------------------------------------- W(f32) -> MFMA B-fragment order, split hi/lo bf16
__global__ void k_make_frags(const float* __restrict__ W,
                             const float* __restrict__ Wr,
                             unsigned short* __restrict__ Whi, unsigned short* __restrict__ Wlo,
                             unsigned short* __restrict__ Wrhi, unsigned short* __restrict__ Wrlo) {
    int t = blockIdx.x * blockDim.x + threadIdx.x;   // 0..4095
    if (t >= 4096) return;
    int mat = t >> 11;
    int fragIdx = (t >> 6) & 31;
    int lane = t & 63;
    int nt = fragIdx >> 2, ks = fragIdx & 3;
    const float* Wsrc = mat ? Wr : W;
    unsigned short* dhi = mat ? Wrhi : Whi;
    unsigned short* dlo = mat ? Wrlo : Wlo;
    int n = nt * 16 + (lane & 15);
    int kbase = ks * 32 + (lane >> 4) * 8;
    short hi[8], lo[8];
#pragma unroll
    for (int j = 0; j < 8; j++) splitbf(Wsrc[(kbase + j) * D + n], hi[j], lo[j]);
    ((uint4*)dhi)[fragIdx * 64 + lane] = *(uint4*)hi;
    ((uint4*)dlo)[fragIdx * 64 + lane] = *(uint4*)lo;
}

// ---------------------------------------------------------------- FUSED gather + dual GEMM  (r8 structure, verbatim)
// Proven best: 77.5 µs, FETCH 127 MB, WRITE 51 MB, VGPR 128, no spills.
// Chunk-8 gather with SHORT-LIVED row registers (r9/r10 lesson: any row data held
// across the MFMA/epilogue spills to scratch — FETCH 452/225 MB regressions).
// Double-buffered LDS A-tile, ONE barrier per tile; next tile's gather overlaps
// this tile's MFMA+epilogue at the wave level. Bank swizzle: slot ^= (row&7).
// DO NOT raise launch_bounds min-waves (r6: (256,4) evicted the weight set).
// Plain launch, grid 1024 (3 blocks/CU at LDS 41 KB; coop's 512 cost 1/3 of them).
__global__ __launch_bounds__(256, 2) void k_fused(
    const float* __restrict__ x,
    const int* __restrict__ esorted, const int* __restrict__ rowStart,
    const float* __restrict__ c_src, const float* __restrict__ c_dst,
    const unsigned short* __restrict__ Whi, const unsigned short* __restrict__ Wlo,
    const unsigned short* __restrict__ Wrhi, const unsigned short* __restrict__ Wrlo,
    const float* __restrict__ bias_h, const float* __restrict__ bias_r,
    float* __restrict__ yout,
    float* __restrict__ gsum, float* __restrict__ gsq) {
    __shared__ uint4 A[2][16][64];    // 32 KB double-buffered A-tile
    __shared__ float Y[4][16 * 36];   // 9.2 KB per-wave private staging

    const int wave = threadIdx.x >> 6;
    const int lane = threadIdx.x & 63;
    const int quad = lane >> 4;
    const int l16 = lane & 15;
    float* __restrict__ ldsY = &Y[wave][0];

    // ---- preload this wave's 32-col weight frags into VGPRs (128 VGPR)
    short8 wHf[8], wLf[8], rHf[8], rLf[8];
#pragma unroll
    for (int f = 0; f < 8; f++) {
        int nt = wave * 2 + (f >> 2), ks = f & 3;
        int gi = (nt * 4 + ks) * 64 + lane;
        wHf[f] = __builtin_bit_cast(short8, ((const uint4*)Whi)[gi]);
        wLf[f] = __builtin_bit_cast(short8, ((const uint4*)Wlo)[gi]);
        rHf[f] = __builtin_bit_cast(short8, ((const uint4*)Wrhi)[gi]);
        rLf[f] = __builtin_bit_cast(short8, ((const uint4*)Wrlo)[gi]);
    }
    float bh[2], brr[2];
#pragma unroll
    for (int ntl = 0; ntl < 2; ntl++) {
        int col = wave * 32 + ntl * 16 + l16;
        bh[ntl] = bias_h[col];
        brr[ntl] = bias_r[col];
    }

    float s_acc[2] = {0.f, 0.f}, q_acc[2] = {0.f, 0.f};
    const f32x4* __restrict__ xb = (const f32x4*)x;   // 32 f32x4 per node row

    int buf = 0;
    for (int rt = blockIdx.x; rt < NTILES; rt += gridDim.x, buf ^= 1) {
        const int rowbase = rt * 16;

        // ================= phase A: quad-gather node rowbase + wave*4 + quad (chunk-8)
        {
            const int R = wave * 4 + quad;          // row within tile
            const int n = rowbase + R;
            const int li = l16;                     // feature octet index
            const int beg = rowStart[n], end = rowStart[n + 1];
            // residual x-row: issue first so it's in flight under the edge loop
            f32x4 X0 = xb[(size_t)n * 32 + li * 2], X1 = xb[(size_t)n * 32 + li * 2 + 1];
            f32x4 A0 = {0.f, 0.f, 0.f, 0.f}, A1 = {0.f, 0.f, 0.f, 0.f};
            for (int j = beg; j < end; j += 8) {
                int idx[8];
                float c[8];
                f32x4 pa[8], pb[8];
#pragma unroll
                for (int k = 0; k < 8; k++) {
                    int jj = j + k;
                    idx[k] = esorted[(jj < end) ? jj : j];   // dup edge-0 pad (cache hit)
                }
#pragma unroll
                for (int k = 0; k < 8; k++)
                    c[k] = (j + k < end) ? c_src[idx[k]] : 0.f;
                // 16 independent 16B loads in flight -> one HBM latency per round
#pragma unroll
                for (int k = 0; k < 8; k++) {
                    pa[k] = xb[(size_t)idx[k] * 32 + li * 2];
                    pb[k] = xb[(size_t)idx[k] * 32 + li * 2 + 1];
                }
#pragma unroll
                for (int k = 0; k < 8; k++) {
                    A0 += pa[k] * c[k];
                    A1 += pb[k] * c[k];
                }
            }
            float cd = c_dst[n];
            A0 *= cd; A1 *= cd;
            uint4 ahi, alo, xhi, xlo;
            split8(A0, A1, ahi, alo);
            split8(X0, X1, xhi, xlo);
            uint4* Arow = &A[buf][R][0];
            const int sw = li ^ (R & 7);            // bank swizzle
            Arow[sw] = ahi;
            Arow[16 + sw] = alo;
            Arow[32 + sw] = xhi;
            Arow[48 + sw] = xlo;
        }
        __syncthreads();   // A-tile writes visible; double-buffer -> only barrier needed

        // ================= phase B: MFMA from LDS A-tile
        const uint4* rowA = &A[buf][l16][0];
        const int r7 = l16 & 7;
        short8 aH[4], aL[4], xH[4], xL[4];
#pragma unroll
        for (int ks = 0; ks < 4; ks++) {
            const int sl = (ks * 4 + quad) ^ r7;
            aH[ks] = __builtin_bit_cast(short8, rowA[sl]);
            aL[ks] = __builtin_bit_cast(short8, rowA[16 + sl]);
            xH[ks] = __builtin_bit_cast(short8, rowA[32 + sl]);
            xL[ks] = __builtin_bit_cast(short8, rowA[48 + sl]);
        }

        f32x4 accH[2], accR[2];
#pragma unroll
        for (int ntl = 0; ntl < 2; ntl++) {
            accH[ntl] = f32x4{0.f, 0.f, 0.f, 0.f};
            accR[ntl] = f32x4{0.f, 0.f, 0.f, 0.f};
#pragma unroll
            for (int ks = 0; ks < 4; ks++) {
                const int f = ntl * 4 + ks;
                accH[ntl] = __builtin_amdgcn_mfma_f32_16x16x32_bf16(aH[ks], wHf[f], accH[ntl], 0, 0, 0);
                accH[ntl] = __builtin_amdgcn_mfma_f32_16x16x32_bf16(aH[ks], wLf[f], accH[ntl], 0, 0, 0);
                accH[ntl] = __builtin_amdgcn_mfma_f32_16x16x32_bf16(aL[ks], wHf[f], accH[ntl], 0, 0, 0);
                accR[ntl] = __builtin_amdgcn_mfma_f32_16x16x32_bf16(xH[ks], rHf[f], accR[ntl], 0, 0, 0);
                accR[ntl] = __builtin_amdgcn_mfma_f32_16x16x32_bf16(xH[ks], rLf[f], accR[ntl], 0, 0, 0);
                accR[ntl] = __builtin_amdgcn_mfma_f32_16x16x32_bf16(xL[ks], rHf[f], accR[ntl], 0, 0, 0);
            }
        }

        // ---- epilogue: per-wave LDS staging + BN partials (no cross-wave sync)
#pragma unroll
        for (int ntl = 0; ntl < 2; ntl++) {
            float s = 0.f, q = 0.f;
#pragma unroll
            for (int r = 0; r < 4; r++) {
                float y = fmaxf(accH[ntl][r] + bh[ntl], 0.f) + fmaxf(accR[ntl][r] + brr[ntl], 0.f);
                ldsY[(quad * 4 + r) * 36 + ntl * 16 + l16] = y;
                s += y;
                q += y * y;
            }
            s_acc[ntl] += s;
            q_acc[ntl] += q;
        }
        asm volatile("s_waitcnt lgkmcnt(0)");
#pragma unroll
        for (int j = 0; j < 2; j++) {
            int trow = j * 8 + (lane >> 3);
            int tc4 = lane & 7;
            float4 v = *(const float4*)&ldsY[trow * 36 + tc4 * 4];
            ((float4*)(yout + (size_t)(rowbase + trow) * D + wave * 32))[tc4] = v;
        }
        // no trailing barrier: next iter writes A[buf^1]; per-iter barrier keeps all
        // waves within one iteration, so A[buf] reads finish before its next write
    }

    // ---- per-wave stats: quads hold same column set
#pragma unroll
    for (int ntl = 0; ntl < 2; ntl++) {
        float s = s_acc[ntl], q = q_acc[ntl];
        s += __shfl_xor(s, 16, 64);
        s += __shfl_xor(s, 32, 64);
        q += __shfl_xor(q, 16, 64);
        q += __shfl_xor(q, 32, 64);
        if (lane < 16) {
            unsafeAtomicAdd(&gsum[wave * 32 + ntl * 16 + lane], s);
            unsafeAtomicAdd(&gsq[wave * 32 + ntl * 16 + lane], q);
        }
    }
}

// ---------------------------------------------------------------- BN stats + apply, merged
// Each block recomputes the 128-float scale/shift from gsum/gsq in LDS (512 B of
// L2-hot reads — trivial), then grid-strides the apply. Removes k_bn_stats launch
// and the scale/shift global round-trip.
__global__ void k_bn_apply(float* __restrict__ y,
                           const float* __restrict__ gsum, const float* __restrict__ gsq,
                           const float* __restrict__ gamma, const float* __restrict__ beta) {
    __shared__ float sc[128], sh[128];
    if (threadIdx.x < 128) {
        int f = threadIdx.x;
        const float invN = 1.0f / (float)N_NODES;
        float mean = gsum[f] * invN;
        float var = fmaxf(gsq[f] * invN - mean * mean, 0.f);
        float s = gamma[f] * rsqrtf(var + BN_EPS);
        sc[f] = s;
        sh[f] = beta[f] - mean * s;
    }
    __syncthreads();
    const int total4 = N_NODES * D / 4;
    for (int i = blockIdx.x * blockDim.x + threadIdx.x; i < total4; i += gridDim.x * blockDim.x) {
        float4 v = ((float4*)y)[i];
        int f = (i * 4) & (D - 1);
        v.x = v.x * sc[f] + sh[f];
        v.y = v.y * sc[f + 1] + sh[f + 1];
        v.z = v.z * sc[f + 2] + sh[f + 2];
        v.w = v.w * sc[f + 3] + sh[f + 3];
        ((float4*)y)[i] = v;
    }
}

// ---------------------------------------------------------------- launch
extern "C" void kernel_launch(void* const* d_in, const int* in_sizes, int n_in,
                              void* d_out, int out_size, void* d_ws, size_t ws_size,
                              hipStream_t stream) {
    const float* x     = (const float*)d_in[0];   // node_feats f32 [N,128]
    const float* W     = (const float*)d_in[1];
    const float* b     = (const float*)d_in[2];
    const float* Wr    = (const float*)d_in[3];
    const float* br    = (const float*)d_in[4];
    const float* gamma = (const float*)d_in[5];
    const float* beta  = (const float*)d_in[6];
    const int* src = (const int*)d_in[7];
    const int* dst = (const int*)d_in[8];
    float* out = (float*)d_out;

    const int NB1 = (N_NODES + 255) / 256;   // 391 scan blocks

    char* ws = (char*)d_ws;
    size_t off = 0;
    // ---- zeroed prefix (one contiguous memset, ~0.8 MB) ----
    float* gsum    = (float*)(ws + off); off += 512;
    float* gsq     = (float*)(ws + off); off += 512;
    int* cnt_src   = (int*)(ws + off); off += 400128;   // N*4 padded to 256
    int* cnt_dst   = (int*)(ws + off); off += 400128;
    const size_t zero_bytes = off;
    // ---- non-zeroed scratch ----
    int* fill      = (int*)(ws + off); off += 400128;   // zeroed by k_scan1
    int* rowStart  = (int*)(ws + off); off += 400384;   // (N+1)*4 padded
    int* bsum      = (int*)(ws + off); off += 2048;     // NB1*4 padded
    int* esorted   = (int*)(ws + off); off += (size_t)N_EDGES * 4;   // 1.6 MB
    float* c_src   = (float*)(ws + off); off += 400128;
    float* c_dst   = (float*)(ws + off); off += 400128;
    unsigned short* WhiF  = (unsigned short*)(ws + off); off += 32768;
    unsigned short* WloF  = (unsigned short*)(ws + off); off += 32768;
    unsigned short* WrhiF = (unsigned short*)(ws + off); off += 32768;
    unsigned short* WrloF = (unsigned short*)(ws + off); off += 32768;
    const size_t needed = off;   // ~4.3 MB

    if (ws_size < needed) {
        k_zero_out<<<(N_NODES * D / 4 + 255) / 256, 256, 0, stream>>>(out, N_NODES * D / 4);
        return;
    }

    hipMemsetAsync(d_ws, 0, zero_bytes, stream);

    k_make_frags<<<16, 256, 0, stream>>>(W, Wr, WhiF, WloF, WrhiF, WrloF);
    // ---- counting sort of edges by dst ----
    k_count<<<(N_EDGES + 255) / 256, 256, 0, stream>>>(src, dst, cnt_src, cnt_dst);
    k_scan1<<<NB1, 256, 0, stream>>>(cnt_dst, rowStart, bsum, cnt_src, c_src, c_dst, fill);
    k_scan2<<<1, 512, 0, stream>>>(bsum, NB1);
    k_scan3<<<NB1, 256, 0, stream>>>(rowStart, bsum);
    k_fill<<<(N_EDGES + 255) / 256, 256, 0, stream>>>(src, dst, rowStart, fill, esorted);
    // ---- fused gather (chunk-8) + dual GEMM + relu + add + BN partials ----
    k_fused<<<1024, 256, 0, stream>>>(x, esorted, rowStart, c_src, c_dst,
                                      WhiF, WloF, WrhiF, WrloF, b, br, out, gsum, gsq);
    // ---- BN stats + apply (merged) ----
    k_bn_apply<<<2048, 256, 0, stream>>>(out, gsum, gsq, gamma, beta);
}